// Round 2
// baseline (705.937 us; speedup 1.0000x reference)
//
#include <hip/hip_runtime.h>
#include <hip/hip_bf16.h>
#include <cstdint>

#define B_ 8
#define T_ 2048
#define E_ 256
#define K_ 512
#define KS_ 9
#define L_ 8192
#define PAD_ 4
#define TP_ (T_ + 2 * PAD_)   // 2056
#define KK_ (E_ * KS_)        // 2304

// fp8 scaling: feats stored as fp8*64, U/final stored as fp8*16.
// S and V accumulators are 1024x true value -> multiply by 2^-10 in epilogue.
#define FEAT_SCALE 64.0f
#define W_SCALE 16.0f
#define INV_SS 9.765625e-4f   // 2^-10

typedef __bf16 bf16x8 __attribute__((ext_vector_type(8)));
typedef float f32x4 __attribute__((ext_vector_type(4)));

__device__ __forceinline__ unsigned short f2bf(float f) {
  union { float f; unsigned int u; } a; a.f = f;
  unsigned int r = (a.u + 0x7FFFu + ((a.u >> 16) & 1u)) >> 16;
  return (unsigned short)r;
}

__device__ __forceinline__ unsigned char f2fp8(float v) {
  return (unsigned char)(__builtin_amdgcn_cvt_pk_fp8_f32(v, v, 0, false) & 0xFF);
}

__device__ __forceinline__ unsigned int pk4_fp8(float a, float b, float c, float d) {
  int v = __builtin_amdgcn_cvt_pk_fp8_f32(a, b, 0, false);
  v = __builtin_amdgcn_cvt_pk_fp8_f32(c, d, v, true);
  return (unsigned int)v;
}

__device__ __forceinline__ void gld_lds16(const void* g, void* l) {
  __builtin_amdgcn_global_load_lds(
      (const __attribute__((address_space(1))) unsigned int*)g,
      (__attribute__((address_space(3))) unsigned int*)l, 16, 0, 0);
}

__device__ __forceinline__ f32x4 mfma_bf16(bf16x8 a, bf16x8 b, f32x4 c) {
  return __builtin_amdgcn_mfma_f32_16x16x32_bf16(a, b, c, 0, 0, 0);
}

__device__ __forceinline__ f32x4 mfma_fp8(long long a, long long b, f32x4 c) {
  return __builtin_amdgcn_mfma_f32_16x16x32_fp8_fp8(a, b, c, 0, 0, 0);
}

// bf16 tile swizzle (conv kernel): chunk offset in shorts, 2-way conflict-free
__device__ __forceinline__ int frag_off(int r, int q) {
  return (4 * r + ((q + (r >> 1)) & 3)) * 8;
}

// ---------------- prep: embed gather + zero halo, cast to bf16 ----------------
__global__ __launch_bounds__(256) void k_embed(const int* __restrict__ ids,
                                               const float* __restrict__ emb,
                                               unsigned short* __restrict__ xpad) {
  int gid = blockIdx.x * 256 + threadIdx.x;
  int row = gid >> 6;
  int e4 = (gid & 63) << 2;
  int b = row / TP_;
  int tp = row - b * TP_;
  float4 v = make_float4(0.f, 0.f, 0.f, 0.f);
  if (tp >= PAD_ && tp < T_ + PAD_) {
    int id = ids[b * T_ + tp - PAD_];
    v = *(const float4*)(emb + (size_t)id * E_ + e4);
  }
  ushort4 o;
  o.x = f2bf(v.x); o.y = f2bf(v.y); o.z = f2bf(v.z); o.w = f2bf(v.w);
  *(ushort4*)(xpad + (size_t)row * E_ + e4) = o;
}

// ---------------- prep: conv_w [K,E,KS] -> W_t [K][j*256+e] bf16 ----------------
__global__ __launch_bounds__(256) void k_wt(const float* __restrict__ conv_w,
                                            unsigned short* __restrict__ wt) {
  int kk = blockIdx.x * 256 + threadIdx.x;
  int k = blockIdx.y;
  int j = kk >> 8, e = kk & 255;
  wt[(size_t)k * KK_ + kk] = f2bf(conv_w[(k * E_ + e) * KS_ + j]);
}

// ---------------- prep: U_w / final_w fp32 -> fp8 (x16) ----------------
__global__ __launch_bounds__(256) void k_cast(const float* __restrict__ U_w,
                                              const float* __restrict__ F_w,
                                              unsigned char* __restrict__ u8,
                                              unsigned char* __restrict__ f8) {
  int gid = blockIdx.x * 256 + threadIdx.x;
  const float* src = blockIdx.y ? F_w : U_w;
  unsigned char* dst = blockIdx.y ? f8 : u8;
  size_t base = (size_t)gid * 8;
  float4 v0 = *(const float4*)(src + base);
  float4 v1 = *(const float4*)(src + base + 4);
  uint2 o;
  o.x = pk4_fp8(v0.x * W_SCALE, v0.y * W_SCALE, v0.z * W_SCALE, v0.w * W_SCALE);
  o.y = pk4_fp8(v1.x * W_SCALE, v1.y * W_SCALE, v1.z * W_SCALE, v1.w * W_SCALE);
  *(uint2*)(dst + base) = o;
}

// ---------------- conv1d as MFMA GEMM (bf16 in, fp8 out x64) ----------------
__global__ __launch_bounds__(256) void k_conv(const unsigned short* __restrict__ xpad,
                                              const unsigned short* __restrict__ wt,
                                              const float* __restrict__ conv_b,
                                              unsigned char* __restrict__ feats) {
  __shared__ short At[128 * 32];
  __shared__ short Bt[128 * 32];
  const int tid = threadIdx.x;
  const int w = tid >> 6, lane = tid & 63;
  const int q = lane >> 4, c = lane & 15;
  const int wi = w >> 1, wj = w & 1;
  const int b = blockIdx.z;
  const int t0 = blockIdx.y * 128;
  const int n0 = blockIdx.x * 128;

  f32x4 acc[4][4];
  f32x4 zero = {0.f, 0.f, 0.f, 0.f};
#pragma unroll
  for (int i = 0; i < 4; ++i)
#pragma unroll
    for (int j = 0; j < 4; ++j) acc[i][j] = zero;

  const unsigned short* xb = xpad + (size_t)b * TP_ * E_;

  for (int kkc = 0; kkc < KK_; kkc += 32) {
    __syncthreads();
    const int jconv = kkc >> 8;
    const int ebase = kkc & 255;
#pragma unroll
    for (int rnd = 0; rnd < 2; ++rnd) {
      int s = rnd * 256 + tid;
      int r = s >> 2;
      int qq = ((s & 3) - (r >> 1)) & 3;
      int ldsoff = (w * 64 + rnd * 256) * 8;
      gld_lds16(xb + (size_t)(t0 + r + jconv) * E_ + ebase + 8 * qq, (void*)(At + ldsoff));
      gld_lds16(wt + (size_t)(n0 + r) * KK_ + kkc + 8 * qq, (void*)(Bt + ldsoff));
    }
    __syncthreads();
    bf16x8 afr[4];
#pragma unroll
    for (int li = 0; li < 4; ++li) {
      int r = wi * 64 + li * 16 + c;
      afr[li] = *(const bf16x8*)(At + frag_off(r, q));
    }
#pragma unroll
    for (int ti = 0; ti < 4; ++ti) {
      int r = wj * 64 + ti * 16 + c;
      bf16x8 bfr = *(const bf16x8*)(Bt + frag_off(r, q));
#pragma unroll
      for (int li = 0; li < 4; ++li)
        acc[li][ti] = mfma_bf16(afr[li], bfr, acc[li][ti]);
    }
  }

#pragma unroll
  for (int ti = 0; ti < 4; ++ti) {
    int k = n0 + wj * 64 + ti * 16 + c;
    float bias = conv_b[k];
#pragma unroll
    for (int li = 0; li < 4; ++li) {
      int tb = t0 + wi * 64 + li * 16 + q * 4;
#pragma unroll
      for (int rr = 0; rr < 4; ++rr) {
        float v = fmaxf(acc[li][ti][rr] + bias, 0.f) * FEAT_SCALE;
        feats[((size_t)(b * T_ + tb + rr)) * K_ + k] = f2fp8(v);
      }
    }
  }
}

// ---------------- fused label-attention, fp8 operands, double-buffered LDS ----------------
__global__ __launch_bounds__(256) void k_attn(const unsigned char* __restrict__ feats,
                                              const unsigned char* __restrict__ u8,
                                              const unsigned char* __restrict__ f8,
                                              const float* __restrict__ final_b,
                                              float* __restrict__ out) {
  __shared__ char Ft[2][4096];
  __shared__ char Ut[2][4096];
  __shared__ char Wt[2][4096];
  __shared__ float red[512];
  const int tid = threadIdx.x;
  const int w = tid >> 6, lane = tid & 63;
  const int q = lane >> 4, c = lane & 15;
  const int wi = w >> 1, wj = w & 1;
  const int b = blockIdx.y;
  const int l0 = blockIdx.x * 128;

  const unsigned char* fb = feats + (size_t)b * T_ * K_;

  // staging geometry: thread stages LDS unit p=tid (16 B at p*16).
  // unit p holds global (row r = p>>1, 16B half h = (p&1)^((r>>2)&1)).
  const int pr = tid >> 1;
  const int ph = ((tid & 1) ^ ((pr >> 2) & 1)) * 16;
  const unsigned char* fsrc = fb + (size_t)pr * K_ + ph;    // + t0*K_ + kc
  const unsigned char* usrc = u8 + (size_t)(l0 + pr) * K_ + ph;  // + kc
  const unsigned char* wsrc = f8 + (size_t)(l0 + pr) * K_ + ph;  // + kc

  // frag read: row rr, chunk q -> byte off rr*32 + ((q>>1)^((rr>>2)&1))*16 + (q&1)*8
  // (rr>>2)&1 == (c>>2)&1 for all li/ti (row steps of 16 preserve bit2 of rr>>2... of rr>>2 parity)
  const int par = (c >> 2) & 1;
  const int fo = (((q >> 1) ^ par) << 4) + ((q & 1) << 3);

  float num_acc[4][4], den_acc[4][4];
#pragma unroll
  for (int li = 0; li < 4; ++li)
#pragma unroll
    for (int rr = 0; rr < 4; ++rr) { num_acc[li][rr] = 0.f; den_acc[li][rr] = 0.f; }

  f32x4 accS[4][4], accV[4][4];
  f32x4 zero = {0.f, 0.f, 0.f, 0.f};
#pragma unroll
  for (int i = 0; i < 4; ++i)
#pragma unroll
    for (int j = 0; j < 4; ++j) { accS[i][j] = zero; accV[i][j] = zero; }

  // stage iteration 0 (t0=0, kc=0) into buffer 0
  gld_lds16(fsrc, Ft[0] + tid * 16);
  gld_lds16(usrc, Ut[0] + tid * 16);
  gld_lds16(wsrc, Wt[0] + tid * 16);

  // flattened (t0, kc) loop: it = t0idx*16 + kcidx
  for (int it = 0; it < 256; ++it) {
    const int bsel = it & 1;
    __syncthreads();   // buf[bsel] staged (vmcnt drain); prior reads of buf[bsel^1] done
    if (it != 255) {
      const int nit = it + 1;
      const int nofs = ((nit >> 4) << 7) * K_ + ((nit & 15) << 5);
      const int nkc = (nit & 15) << 5;
      gld_lds16(fsrc + nofs, Ft[bsel ^ 1] + tid * 16);
      gld_lds16(usrc + nkc, Ut[bsel ^ 1] + tid * 16);
      gld_lds16(wsrc + nkc, Wt[bsel ^ 1] + tid * 16);
    }
    long long au[4], aw[4];
#pragma unroll
    for (int li = 0; li < 4; ++li) {
      int off = (wi * 64 + li * 16 + c) * 32 + fo;
      au[li] = *(const long long*)(Ut[bsel] + off);
      aw[li] = *(const long long*)(Wt[bsel] + off);
    }
#pragma unroll
    for (int ti = 0; ti < 4; ++ti) {
      int boff = (wj * 64 + ti * 16 + c) * 32 + fo;
      long long bfr = *(const long long*)(Ft[bsel] + boff);
#pragma unroll
      for (int li = 0; li < 4; ++li) {
        accS[li][ti] = mfma_fp8(au[li], bfr, accS[li][ti]);
        accV[li][ti] = mfma_fp8(aw[li], bfr, accV[li][ti]);
      }
    }
    if ((it & 15) == 15) {
      // end of K for this t-tile: softmax-weighted accumulate, reset accs.
      // scores are O(0.01) -> exp without max-shift is safe.
#pragma unroll
      for (int li = 0; li < 4; ++li)
#pragma unroll
        for (int ti = 0; ti < 4; ++ti)
#pragma unroll
          for (int rr = 0; rr < 4; ++rr) {
            float p = __expf(accS[li][ti][rr] * INV_SS);
            den_acc[li][rr] += p;
            num_acc[li][rr] += p * (accV[li][ti][rr] * INV_SS);
            accS[li][ti][rr] = 0.f;
            accV[li][ti][rr] = 0.f;
          }
    }
  }

  // 16-lane (t-column) butterfly reduce
#pragma unroll
  for (int li = 0; li < 4; ++li)
#pragma unroll
    for (int rr = 0; rr < 4; ++rr) {
      float n = num_acc[li][rr], d = den_acc[li][rr];
#pragma unroll
      for (int m = 1; m < 16; m <<= 1) {
        n += __shfl_xor(n, m, 64);
        d += __shfl_xor(d, m, 64);
      }
      num_acc[li][rr] = n; den_acc[li][rr] = d;
    }
  if (c == 0) {
#pragma unroll
    for (int li = 0; li < 4; ++li)
#pragma unroll
      for (int rr = 0; rr < 4; ++rr) {
        int r = wi * 64 + li * 16 + q * 4 + rr;
        red[wj * 128 + r] = num_acc[li][rr];
        red[(2 + wj) * 128 + r] = den_acc[li][rr];
      }
  }
  __syncthreads();
  if (tid < 128) {
    int l = l0 + tid;
    float n = red[tid] + red[128 + tid];
    float d = red[256 + tid] + red[384 + tid];
    out[(size_t)b * L_ + l] = n / d + final_b[l];
  }
}

// ---------------- BCE-with-logits mean ----------------
__global__ __launch_bounds__(256) void k_loss(const float* __restrict__ yhat,
                                              const float* __restrict__ target,
                                              float* __restrict__ loss) {
  int gid = blockIdx.x * 256 + threadIdx.x;
  float s = 0.f;
  for (int i = gid; i < B_ * L_; i += 64 * 256) {
    float y = yhat[i], t = target[i];
    s += fmaxf(y, 0.f) - y * t + log1pf(__expf(-fabsf(y)));
  }
#pragma unroll
  for (int m = 1; m < 64; m <<= 1) s += __shfl_xor(s, m, 64);
  if ((threadIdx.x & 63) == 0) atomicAdd(loss, s * (1.0f / (B_ * L_)));
}

extern "C" void kernel_launch(void* const* d_in, const int* in_sizes, int n_in,
                              void* d_out, int out_size, void* d_ws, size_t ws_size,
                              hipStream_t stream) {
  const int* ids = (const int*)d_in[0];
  const float* target = (const float*)d_in[3];
  const float* emb = (const float*)d_in[4];
  const float* conv_w = (const float*)d_in[5];
  const float* conv_b = (const float*)d_in[6];
  const float* U_w = (const float*)d_in[7];
  const float* F_w = (const float*)d_in[8];
  const float* final_b = (const float*)d_in[9];
  float* out = (float*)d_out;

  char* ws = (char*)d_ws;
  unsigned short* xpad = (unsigned short*)ws;                    // bf16 B*TP*E
  size_t off = (size_t)B_ * TP_ * E_ * 2;
  unsigned short* wt = (unsigned short*)(ws + off);              // bf16 K*KK
  off += (size_t)K_ * KK_ * 2;
  unsigned char* u8 = (unsigned char*)(ws + off);                // fp8 L*K
  off += (size_t)L_ * K_;
  unsigned char* f8 = (unsigned char*)(ws + off);                // fp8 L*K
  off += (size_t)L_ * K_;
  unsigned char* feats = (unsigned char*)(ws + off);             // fp8 B*T*K
  off += (size_t)B_ * T_ * K_;
  if (ws_size < off) return;

  k_embed<<<dim3((B_ * TP_ * 64) / 256), 256, 0, stream>>>(ids, emb, xpad);
  k_wt<<<dim3(KK_ / 256, K_), 256, 0, stream>>>(conv_w, wt);
  k_cast<<<dim3((L_ * K_ / 8) / 256, 2), 256, 0, stream>>>(U_w, F_w, u8, f8);
  k_conv<<<dim3(K_ / 128, T_ / 128, B_), 256, 0, stream>>>(xpad, wt, conv_b, feats);
  k_attn<<<dim3(L_ / 128, B_), 256, 0, stream>>>(feats, u8, f8, final_b, out);
  hipMemsetAsync(out + B_ * L_, 0, sizeof(float), stream);
  k_loss<<<dim3(64), 256, 0, stream>>>(out, target, out + B_ * L_);
}

// Round 3
// 458.911 us; speedup vs baseline: 1.5383x; 1.5383x over previous
//
#include <hip/hip_runtime.h>
#include <hip/hip_bf16.h>
#include <cstdint>

#define B_ 8
#define T_ 2048
#define E_ 256
#define K_ 512
#define KS_ 9
#define L_ 8192
#define PAD_ 4
#define TP_ (T_ + 2 * PAD_)   // 2056
#define KK_ (E_ * KS_)        // 2304

// fp8 scaling: feats stored as fp8*64, U/final stored as fp8*16.
// S and V accumulators are 1024x true value -> multiply by 2^-10 in epilogue.
#define FEAT_SCALE 64.0f
#define W_SCALE 16.0f
#define INV_SS 9.765625e-4f   // 2^-10

typedef __bf16 bf16x8 __attribute__((ext_vector_type(8)));
typedef float f32x4 __attribute__((ext_vector_type(4)));

__device__ __forceinline__ unsigned short f2bf(float f) {
  union { float f; unsigned int u; } a; a.f = f;
  unsigned int r = (a.u + 0x7FFFu + ((a.u >> 16) & 1u)) >> 16;
  return (unsigned short)r;
}

__device__ __forceinline__ unsigned char f2fp8(float v) {
  return (unsigned char)(__builtin_amdgcn_cvt_pk_fp8_f32(v, v, 0, false) & 0xFF);
}

__device__ __forceinline__ unsigned int pk4_fp8(float a, float b, float c, float d) {
  int v = __builtin_amdgcn_cvt_pk_fp8_f32(a, b, 0, false);
  v = __builtin_amdgcn_cvt_pk_fp8_f32(c, d, v, true);
  return (unsigned int)v;
}

__device__ __forceinline__ void gld_lds16(const void* g, void* l) {
  __builtin_amdgcn_global_load_lds(
      (const __attribute__((address_space(1))) unsigned int*)g,
      (__attribute__((address_space(3))) unsigned int*)l, 16, 0, 0);
}

__device__ __forceinline__ f32x4 mfma_bf16(bf16x8 a, bf16x8 b, f32x4 c) {
  return __builtin_amdgcn_mfma_f32_16x16x32_bf16(a, b, c, 0, 0, 0);
}

__device__ __forceinline__ f32x4 mfma_fp8(long long a, long long b, f32x4 c) {
  return __builtin_amdgcn_mfma_f32_16x16x32_fp8_fp8(a, b, c, 0, 0, 0);
}

// bf16 tile swizzle (conv kernel): chunk offset in shorts, 2-way conflict-free
__device__ __forceinline__ int frag_off(int r, int q) {
  return (4 * r + ((q + (r >> 1)) & 3)) * 8;
}

// ---------------- prep: embed gather + zero halo, cast to bf16 ----------------
__global__ __launch_bounds__(256) void k_embed(const int* __restrict__ ids,
                                               const float* __restrict__ emb,
                                               unsigned short* __restrict__ xpad) {
  int gid = blockIdx.x * 256 + threadIdx.x;
  int row = gid >> 6;
  int e4 = (gid & 63) << 2;
  int b = row / TP_;
  int tp = row - b * TP_;
  float4 v = make_float4(0.f, 0.f, 0.f, 0.f);
  if (tp >= PAD_ && tp < T_ + PAD_) {
    int id = ids[b * T_ + tp - PAD_];
    v = *(const float4*)(emb + (size_t)id * E_ + e4);
  }
  ushort4 o;
  o.x = f2bf(v.x); o.y = f2bf(v.y); o.z = f2bf(v.z); o.w = f2bf(v.w);
  *(ushort4*)(xpad + (size_t)row * E_ + e4) = o;
}

// ---------------- prep: conv_w [K,E,KS] -> W_t [K][j*256+e] bf16 ----------------
__global__ __launch_bounds__(256) void k_wt(const float* __restrict__ conv_w,
                                            unsigned short* __restrict__ wt) {
  int kk = blockIdx.x * 256 + threadIdx.x;
  int k = blockIdx.y;
  int j = kk >> 8, e = kk & 255;
  wt[(size_t)k * KK_ + kk] = f2bf(conv_w[(k * E_ + e) * KS_ + j]);
}

// ---------------- prep: U_w / final_w fp32 -> fp8 (x16) ----------------
__global__ __launch_bounds__(256) void k_cast(const float* __restrict__ U_w,
                                              const float* __restrict__ F_w,
                                              unsigned char* __restrict__ u8,
                                              unsigned char* __restrict__ f8) {
  int gid = blockIdx.x * 256 + threadIdx.x;
  const float* src = blockIdx.y ? F_w : U_w;
  unsigned char* dst = blockIdx.y ? f8 : u8;
  size_t base = (size_t)gid * 8;
  float4 v0 = *(const float4*)(src + base);
  float4 v1 = *(const float4*)(src + base + 4);
  uint2 o;
  o.x = pk4_fp8(v0.x * W_SCALE, v0.y * W_SCALE, v0.z * W_SCALE, v0.w * W_SCALE);
  o.y = pk4_fp8(v1.x * W_SCALE, v1.y * W_SCALE, v1.z * W_SCALE, v1.w * W_SCALE);
  *(uint2*)(dst + base) = o;
}

// ---------------- conv1d as MFMA GEMM (bf16 in, fp8 out x64) ----------------
__global__ __launch_bounds__(256) void k_conv(const unsigned short* __restrict__ xpad,
                                              const unsigned short* __restrict__ wt,
                                              const float* __restrict__ conv_b,
                                              unsigned char* __restrict__ feats) {
  __shared__ short At[128 * 32];
  __shared__ short Bt[128 * 32];
  const int tid = threadIdx.x;
  const int w = tid >> 6, lane = tid & 63;
  const int q = lane >> 4, c = lane & 15;
  const int wi = w >> 1, wj = w & 1;
  const int b = blockIdx.z;
  const int t0 = blockIdx.y * 128;
  const int n0 = blockIdx.x * 128;

  f32x4 acc[4][4];
  f32x4 zero = {0.f, 0.f, 0.f, 0.f};
#pragma unroll
  for (int i = 0; i < 4; ++i)
#pragma unroll
    for (int j = 0; j < 4; ++j) acc[i][j] = zero;

  const unsigned short* xb = xpad + (size_t)b * TP_ * E_;

  for (int kkc = 0; kkc < KK_; kkc += 32) {
    __syncthreads();
    const int jconv = kkc >> 8;
    const int ebase = kkc & 255;
#pragma unroll
    for (int rnd = 0; rnd < 2; ++rnd) {
      int s = rnd * 256 + tid;
      int r = s >> 2;
      int qq = ((s & 3) - (r >> 1)) & 3;
      int ldsoff = (w * 64 + rnd * 256) * 8;
      gld_lds16(xb + (size_t)(t0 + r + jconv) * E_ + ebase + 8 * qq, (void*)(At + ldsoff));
      gld_lds16(wt + (size_t)(n0 + r) * KK_ + kkc + 8 * qq, (void*)(Bt + ldsoff));
    }
    __syncthreads();
    bf16x8 afr[4];
#pragma unroll
    for (int li = 0; li < 4; ++li) {
      int r = wi * 64 + li * 16 + c;
      afr[li] = *(const bf16x8*)(At + frag_off(r, q));
    }
#pragma unroll
    for (int ti = 0; ti < 4; ++ti) {
      int r = wj * 64 + ti * 16 + c;
      bf16x8 bfr = *(const bf16x8*)(Bt + frag_off(r, q));
#pragma unroll
      for (int li = 0; li < 4; ++li)
        acc[li][ti] = mfma_bf16(afr[li], bfr, acc[li][ti]);
    }
  }

#pragma unroll
  for (int ti = 0; ti < 4; ++ti) {
    int k = n0 + wj * 64 + ti * 16 + c;
    float bias = conv_b[k];
#pragma unroll
    for (int li = 0; li < 4; ++li) {
      int tb = t0 + wi * 64 + li * 16 + q * 4;
#pragma unroll
      for (int rr = 0; rr < 4; ++rr) {
        float v = fmaxf(acc[li][ti][rr] + bias, 0.f) * FEAT_SCALE;
        feats[((size_t)(b * T_ + tb + rr)) * K_ + k] = f2fp8(v);
      }
    }
  }
}

// ---------------- fused label-attention: 512 threads, 8 waves (4L x 2T), ----------------
// wave tile 32L x 64T, BK=64, dbuf LDS, 2 waves/SIMD target.
__global__ __launch_bounds__(512, 2) void k_attn(const unsigned char* __restrict__ feats,
                                                 const unsigned char* __restrict__ u8,
                                                 const unsigned char* __restrict__ f8,
                                                 const float* __restrict__ final_b,
                                                 float* __restrict__ out) {
  __shared__ char Ft[2][8192];
  __shared__ char Ut[2][8192];
  __shared__ char Wt[2][8192];
  __shared__ float red[2][256];   // [wj][idx]=num, [wj][128+idx]=den
  const int tid = threadIdx.x;
  const int w = tid >> 6, lane = tid & 63;
  const int q = lane >> 4, c = lane & 15;
  const int wi = w >> 1;   // 0..3 : L quarter (32 rows)
  const int wj = w & 1;    // 0..1 : T half (64 cols)
  const int b = blockIdx.y;
  const int l0 = blockIdx.x * 128;

  const unsigned char* fb = feats + (size_t)b * T_ * K_;

  // staging: wave w stages tile rows [w*16, w*16+16); lane -> (row, 16B pos)
  // LDS 16B slot within 64B row is rotated: j16 = (p + r) & 3
  const int sr = w * 16 + (lane >> 2);          // tile row 0..127
  const int sp = (((lane & 3) - sr) & 3) * 16;  // global byte pos in row
  const unsigned char* fsrc = fb + (size_t)sr * K_ + sp;          // + t-tile ofs + kc
  const unsigned char* usrc = u8 + (size_t)(l0 + sr) * K_ + sp;   // + kc
  const unsigned char* wsrc = f8 + (size_t)(l0 + sr) * K_ + sp;   // + kc
  char* const fdst = (char*)Ft + tid * 16;   // + bsel*8192 handled via index
  char* const udst = (char*)Ut + tid * 16;
  char* const wdst = (char*)Wt + tid * 16;

  // frag read byte offsets: row r, k-step h, q-chunk:
  // off = r*64 + (2*(((2h + (q>>1)) + r) & 3) + (q&1)) * 8
  int offA[2][2], offB[4][2];
#pragma unroll
  for (int li = 0; li < 2; ++li) {
    int r = wi * 32 + li * 16 + c;
#pragma unroll
    for (int h = 0; h < 2; ++h)
      offA[li][h] = r * 64 + (2 * (((2 * h + (q >> 1)) + r) & 3) + (q & 1)) * 8;
  }
#pragma unroll
  for (int ti = 0; ti < 4; ++ti) {
    int r = wj * 64 + ti * 16 + c;
#pragma unroll
    for (int h = 0; h < 2; ++h)
      offB[ti][h] = r * 64 + (2 * (((2 * h + (q >> 1)) + r) & 3) + (q & 1)) * 8;
  }

  float num_acc[2][4], den_acc[2][4];
#pragma unroll
  for (int li = 0; li < 2; ++li)
#pragma unroll
    for (int rr = 0; rr < 4; ++rr) { num_acc[li][rr] = 0.f; den_acc[li][rr] = 0.f; }

  f32x4 accS[2][4], accV[2][4];
  f32x4 zero = {0.f, 0.f, 0.f, 0.f};
#pragma unroll
  for (int i = 0; i < 2; ++i)
#pragma unroll
    for (int j = 0; j < 4; ++j) { accS[i][j] = zero; accV[i][j] = zero; }

  // stage iteration 0 into buffer 0
  gld_lds16(fsrc, fdst);
  gld_lds16(usrc, udst);
  gld_lds16(wsrc, wdst);

  // it = t0idx*8 + kcidx; t-tile 128, kc step 64
  for (int it = 0; it < 128; ++it) {
    const int bsel = it & 1;
    __syncthreads();   // buf[bsel] staged; prior reads of buf[bsel^1] done
    if (it != 127) {
      const int nit = it + 1;
      const int fofs = ((nit >> 3) << 16) + ((nit & 7) << 6);  // t0*K + kc
      const int kofs = (nit & 7) << 6;
      const int nb = (bsel ^ 1) * 8192;
      gld_lds16(fsrc + fofs, fdst + nb);
      gld_lds16(usrc + kofs, udst + nb);
      gld_lds16(wsrc + kofs, wdst + nb);
    }
    const char* uB = Ut[bsel];
    const char* wB = Wt[bsel];
    const char* fB = Ft[bsel];
#pragma unroll
    for (int h = 0; h < 2; ++h) {
      long long au[2], aw[2], bf[4];
#pragma unroll
      for (int li = 0; li < 2; ++li) {
        au[li] = *(const long long*)(uB + offA[li][h]);
        aw[li] = *(const long long*)(wB + offA[li][h]);
      }
#pragma unroll
      for (int ti = 0; ti < 4; ++ti)
        bf[ti] = *(const long long*)(fB + offB[ti][h]);
#pragma unroll
      for (int ti = 0; ti < 4; ++ti)
#pragma unroll
        for (int li = 0; li < 2; ++li) {
          accS[li][ti] = mfma_fp8(au[li], bf[ti], accS[li][ti]);
          accV[li][ti] = mfma_fp8(aw[li], bf[ti], accV[li][ti]);
        }
    }
    if ((it & 7) == 7) {
      // end of K for this t-tile: softmax-weighted accumulate, reset accs.
      // scores are O(0.01): exp without max-shift is safe.
#pragma unroll
      for (int li = 0; li < 2; ++li)
#pragma unroll
        for (int ti = 0; ti < 4; ++ti)
#pragma unroll
          for (int rr = 0; rr < 4; ++rr) {
            float p = __expf(accS[li][ti][rr] * INV_SS);
            den_acc[li][rr] += p;
            num_acc[li][rr] += p * (accV[li][ti][rr] * INV_SS);
            accS[li][ti][rr] = 0.f;
            accV[li][ti][rr] = 0.f;
          }
    }
  }

  // reduce over the 16 t-columns (lanes within q-group)
#pragma unroll
  for (int li = 0; li < 2; ++li)
#pragma unroll
    for (int rr = 0; rr < 4; ++rr) {
      float n = num_acc[li][rr], d = den_acc[li][rr];
#pragma unroll
      for (int m = 1; m < 16; m <<= 1) {
        n += __shfl_xor(n, m, 64);
        d += __shfl_xor(d, m, 64);
      }
      num_acc[li][rr] = n; den_acc[li][rr] = d;
    }
  if (c == 0) {
#pragma unroll
    for (int li = 0; li < 2; ++li)
#pragma unroll
      for (int rr = 0; rr < 4; ++rr) {
        int idx = wi * 32 + li * 16 + q * 4 + rr;   // 0..127
        red[wj][idx] = num_acc[li][rr];
        red[wj][128 + idx] = den_acc[li][rr];
      }
  }
  __syncthreads();
  if (tid < 128) {
    int l = l0 + tid;
    float n = red[0][tid] + red[1][tid];
    float d = red[0][128 + tid] + red[1][128 + tid];
    out[(size_t)b * L_ + l] = n / d + final_b[l];
  }
}

// ---------------- BCE-with-logits mean ----------------
__global__ __launch_bounds__(256) void k_loss(const float* __restrict__ yhat,
                                              const float* __restrict__ target,
                                              float* __restrict__ loss) {
  int gid = blockIdx.x * 256 + threadIdx.x;
  float s = 0.f;
  for (int i = gid; i < B_ * L_; i += 64 * 256) {
    float y = yhat[i], t = target[i];
    s += fmaxf(y, 0.f) - y * t + log1pf(__expf(-fabsf(y)));
  }
#pragma unroll
  for (int m = 1; m < 64; m <<= 1) s += __shfl_xor(s, m, 64);
  if ((threadIdx.x & 63) == 0) atomicAdd(loss, s * (1.0f / (B_ * L_)));
}

extern "C" void kernel_launch(void* const* d_in, const int* in_sizes, int n_in,
                              void* d_out, int out_size, void* d_ws, size_t ws_size,
                              hipStream_t stream) {
  const int* ids = (const int*)d_in[0];
  const float* target = (const float*)d_in[3];
  const float* emb = (const float*)d_in[4];
  const float* conv_w = (const float*)d_in[5];
  const float* conv_b = (const float*)d_in[6];
  const float* U_w = (const float*)d_in[7];
  const float* F_w = (const float*)d_in[8];
  const float* final_b = (const float*)d_in[9];
  float* out = (float*)d_out;

  char* ws = (char*)d_ws;
  unsigned short* xpad = (unsigned short*)ws;                    // bf16 B*TP*E
  size_t off = (size_t)B_ * TP_ * E_ * 2;
  unsigned short* wt = (unsigned short*)(ws + off);              // bf16 K*KK
  off += (size_t)K_ * KK_ * 2;
  unsigned char* u8 = (unsigned char*)(ws + off);                // fp8 L*K
  off += (size_t)L_ * K_;
  unsigned char* f8 = (unsigned char*)(ws + off);                // fp8 L*K
  off += (size_t)L_ * K_;
  unsigned char* feats = (unsigned char*)(ws + off);             // fp8 B*T*K
  off += (size_t)B_ * T_ * K_;
  if (ws_size < off) return;

  k_embed<<<dim3((B_ * TP_ * 64) / 256), 256, 0, stream>>>(ids, emb, xpad);
  k_wt<<<dim3(KK_ / 256, K_), 256, 0, stream>>>(conv_w, wt);
  k_cast<<<dim3((L_ * K_ / 8) / 256, 2), 256, 0, stream>>>(U_w, F_w, u8, f8);
  k_conv<<<dim3(K_ / 128, T_ / 128, B_), 256, 0, stream>>>(xpad, wt, conv_b, feats);
  k_attn<<<dim3(L_ / 128, B_), 512, 0, stream>>>(feats, u8, f8, final_b, out);
  hipMemsetAsync(out + B_ * L_, 0, sizeof(float), stream);
  k_loss<<<dim3(64), 256, 0, stream>>>(out, target, out + B_ * L_);
}

// Round 4
// 430.364 us; speedup vs baseline: 1.6403x; 1.0663x over previous
//
#include <hip/hip_runtime.h>
#include <hip/hip_bf16.h>
#include <cstdint>

#define B_ 8
#define T_ 2048
#define E_ 256
#define K_ 512
#define KS_ 9
#define L_ 8192
#define PAD_ 4
#define TP_ (T_ + 2 * PAD_)   // 2056
#define KK_ (E_ * KS_)        // 2304

// fp8 scaling: feats stored as fp8*64, U/final stored as fp8*16.
// S and V accumulators are 1024x true value -> multiply by 2^-10 in epilogue.
#define FEAT_SCALE 64.0f
#define W_SCALE 16.0f
#define INV_SS 9.765625e-4f   // 2^-10

typedef __bf16 bf16x8 __attribute__((ext_vector_type(8)));
typedef float f32x4 __attribute__((ext_vector_type(4)));
typedef float f32x16 __attribute__((ext_vector_type(16)));

__device__ __forceinline__ unsigned short f2bf(float f) {
  union { float f; unsigned int u; } a; a.f = f;
  unsigned int r = (a.u + 0x7FFFu + ((a.u >> 16) & 1u)) >> 16;
  return (unsigned short)r;
}

__device__ __forceinline__ unsigned char f2fp8(float v) {
  return (unsigned char)(__builtin_amdgcn_cvt_pk_fp8_f32(v, v, 0, false) & 0xFF);
}

__device__ __forceinline__ unsigned int pk4_fp8(float a, float b, float c, float d) {
  int v = __builtin_amdgcn_cvt_pk_fp8_f32(a, b, 0, false);
  v = __builtin_amdgcn_cvt_pk_fp8_f32(c, d, v, true);
  return (unsigned int)v;
}

__device__ __forceinline__ void gld_lds16(const void* g, void* l) {
  __builtin_amdgcn_global_load_lds(
      (const __attribute__((address_space(1))) unsigned int*)g,
      (__attribute__((address_space(3))) unsigned int*)l, 16, 0, 0);
}

__device__ __forceinline__ f32x4 mfma_bf16(bf16x8 a, bf16x8 b, f32x4 c) {
  return __builtin_amdgcn_mfma_f32_16x16x32_bf16(a, b, c, 0, 0, 0);
}

__device__ __forceinline__ f32x16 mfma32_fp8(long long a, long long b, f32x16 c) {
  return __builtin_amdgcn_mfma_f32_32x32x16_fp8_fp8(a, b, c, 0, 0, 0);
}

// ---------------- prep: embed gather + zero halo, cast to bf16 ----------------
__global__ __launch_bounds__(256) void k_embed(const int* __restrict__ ids,
                                               const float* __restrict__ emb,
                                               unsigned short* __restrict__ xpad) {
  int gid = blockIdx.x * 256 + threadIdx.x;
  int row = gid >> 6;
  int e4 = (gid & 63) << 2;
  int b = row / TP_;
  int tp = row - b * TP_;
  float4 v = make_float4(0.f, 0.f, 0.f, 0.f);
  if (tp >= PAD_ && tp < T_ + PAD_) {
    int id = ids[b * T_ + tp - PAD_];
    v = *(const float4*)(emb + (size_t)id * E_ + e4);
  }
  ushort4 o;
  o.x = f2bf(v.x); o.y = f2bf(v.y); o.z = f2bf(v.z); o.w = f2bf(v.w);
  *(ushort4*)(xpad + (size_t)row * E_ + e4) = o;
}

// ---------------- prep: conv_w [K,E,KS] -> W_t [K][j*256+e] bf16 ----------------
__global__ __launch_bounds__(256) void k_wt(const float* __restrict__ conv_w,
                                            unsigned short* __restrict__ wt) {
  int kk = blockIdx.x * 256 + threadIdx.x;
  int k = blockIdx.y;
  int j = kk >> 8, e = kk & 255;
  wt[(size_t)k * KK_ + kk] = f2bf(conv_w[(k * E_ + e) * KS_ + j]);
}

// ---------------- prep: U_w / final_w fp32 -> fp8 (x16) ----------------
__global__ __launch_bounds__(256) void k_cast(const float* __restrict__ U_w,
                                              const float* __restrict__ F_w,
                                              unsigned char* __restrict__ u8,
                                              unsigned char* __restrict__ f8) {
  int gid = blockIdx.x * 256 + threadIdx.x;
  const float* src = blockIdx.y ? F_w : U_w;
  unsigned char* dst = blockIdx.y ? f8 : u8;
  size_t base = (size_t)gid * 8;
  float4 v0 = *(const float4*)(src + base);
  float4 v1 = *(const float4*)(src + base + 4);
  uint2 o;
  o.x = pk4_fp8(v0.x * W_SCALE, v0.y * W_SCALE, v0.z * W_SCALE, v0.w * W_SCALE);
  o.y = pk4_fp8(v1.x * W_SCALE, v1.y * W_SCALE, v1.z * W_SCALE, v1.w * W_SCALE);
  *(uint2*)(dst + base) = o;
}

// ---------------- conv1d as MFMA GEMM (bf16 in, fp8 out x64) ----------------
// 512 threads = 8 waves (4 t-quarters x 2 k-halves), wave tile 32t x 64k,
// BK=64, double-buffered LDS, XOR-16B swizzle. acc = 32 VGPR -> 4 waves/EU.
__global__ __launch_bounds__(512, 4) void k_conv(const unsigned short* __restrict__ xpad,
                                                 const unsigned short* __restrict__ wt,
                                                 const float* __restrict__ conv_b,
                                                 unsigned char* __restrict__ feats) {
  __shared__ char At[2][16384];
  __shared__ char Bt[2][16384];
  const int tid = threadIdx.x;
  const int lane = tid & 63;
  const int q = lane >> 4, c = lane & 15;
  const int w = tid >> 6;
  const int wi = w >> 1, wj = w & 1;
  const int b = blockIdx.z;
  const int t0 = blockIdx.y * 128;
  const int n0 = blockIdx.x * 128;

  const char* xb = (const char*)(xpad + (size_t)b * TP_ * E_);
  const char* wb = (const char*)wt;

  // staging geometry: 2 rounds per tensor, unit u = rnd*512+tid.
  // row r = u>>3, 16B piece j stored at slot j^(r&7).
  const char* asrc[2]; const char* bsrc[2]; int ldso[2];
#pragma unroll
  for (int rnd = 0; rnd < 2; ++rnd) {
    int u = rnd * 512 + tid;
    int r = u >> 3;
    int j = (u & 7) ^ (r & 7);
    asrc[rnd] = xb + (size_t)(t0 + r) * 512 + j * 16;
    bsrc[rnd] = wb + (size_t)(n0 + r) * (KK_ * 2) + j * 16;
    ldso[rnd] = u * 16;
  }

  // frag read offsets [idx][h]: row*128 + ((4h+q)^(row&7))*16
  int offA[2][2], offB[4][2];
#pragma unroll
  for (int li = 0; li < 2; ++li) {
    int r = wi * 32 + li * 16 + c;
#pragma unroll
    for (int h = 0; h < 2; ++h) offA[li][h] = r * 128 + (((4 * h + q) ^ (r & 7)) << 4);
  }
#pragma unroll
  for (int ti = 0; ti < 4; ++ti) {
    int r = wj * 64 + ti * 16 + c;
#pragma unroll
    for (int h = 0; h < 2; ++h) offB[ti][h] = r * 128 + (((4 * h + q) ^ (r & 7)) << 4);
  }

  f32x4 acc[2][4];
  f32x4 zero = {0.f, 0.f, 0.f, 0.f};
#pragma unroll
  for (int i = 0; i < 2; ++i)
#pragma unroll
    for (int j = 0; j < 4; ++j) acc[i][j] = zero;

  // stage it 0 into buffer 0
#pragma unroll
  for (int rnd = 0; rnd < 2; ++rnd) {
    gld_lds16(asrc[rnd], At[0] + ldso[rnd]);
    gld_lds16(bsrc[rnd], Bt[0] + ldso[rnd]);
  }

  for (int it = 0; it < 36; ++it) {
    const int bsel = it & 1;
    __syncthreads();
    if (it != 35) {
      const int kkc = (it + 1) * 64;
      const int aofs = (kkc >> 8) * 512 + (kkc & 255) * 2;
      const int bofs = kkc * 2;
#pragma unroll
      for (int rnd = 0; rnd < 2; ++rnd) {
        gld_lds16(asrc[rnd] + aofs, At[bsel ^ 1] + ldso[rnd]);
        gld_lds16(bsrc[rnd] + bofs, Bt[bsel ^ 1] + ldso[rnd]);
      }
    }
    const char* aB = At[bsel];
    const char* bB = Bt[bsel];
#pragma unroll
    for (int h = 0; h < 2; ++h) {
      bf16x8 afr[2], bfr[4];
#pragma unroll
      for (int li = 0; li < 2; ++li) afr[li] = *(const bf16x8*)(aB + offA[li][h]);
#pragma unroll
      for (int ti = 0; ti < 4; ++ti) bfr[ti] = *(const bf16x8*)(bB + offB[ti][h]);
#pragma unroll
      for (int ti = 0; ti < 4; ++ti)
#pragma unroll
        for (int li = 0; li < 2; ++li)
          acc[li][ti] = mfma_bf16(afr[li], bfr[ti], acc[li][ti]);
    }
  }

  // epilogue: +bias, relu, fp8 store. C/D: row(t)=q*4+rr, col(k)=c
#pragma unroll
  for (int ti = 0; ti < 4; ++ti) {
    int k = n0 + wj * 64 + ti * 16 + c;
    float bias = conv_b[k];
#pragma unroll
    for (int li = 0; li < 2; ++li) {
      int tb = t0 + wi * 32 + li * 16 + q * 4;
#pragma unroll
      for (int rr = 0; rr < 4; ++rr) {
        float v = fmaxf(acc[li][ti][rr] + bias, 0.f) * FEAT_SCALE;
        feats[((size_t)(b * T_ + tb + rr)) * K_ + k] = f2fp8(v);
      }
    }
  }
}

// ---------------- fused label-attention ----------------
// 512 threads = 8 waves (4 L-quarters x 2 T-halves), MFMA 32x32x16 fp8.
// U/W A-fragments held in REGISTERS for the whole kernel (t-invariant);
// only the F tile goes through LDS (pair-line XOR swizzle, dbuf, BK=128).
__global__ __launch_bounds__(512, 2) void k_attn(const unsigned char* __restrict__ feats,
                                                 const unsigned char* __restrict__ u8,
                                                 const unsigned char* __restrict__ f8,
                                                 const float* __restrict__ final_b,
                                                 float* __restrict__ out) {
  __shared__ char Ft[2][8192];
  __shared__ float red[512];
  const int tid = threadIdx.x;
  const int lane = tid & 63;
  const int q2 = lane >> 5, c32 = lane & 31;
  const int w = tid >> 6;
  const int wi = w >> 1;   // L quarter (32 rows)
  const int wj = w & 1;    // T half (32 cols of 64-row t-tile)
  const int b = blockIdx.y;
  const int l0 = blockIdx.x * 128;

  const unsigned char* fb = feats + (size_t)b * T_ * K_;

  // ---- load U/W fragments into registers: lane holds row l, bytes ks*16+q2*8 ----
  const int lrow = l0 + wi * 32 + c32;
  const unsigned char* ubase = u8 + (size_t)lrow * K_ + q2 * 8;
  const unsigned char* wbase = f8 + (size_t)lrow * K_ + q2 * 8;
  long long uf[32], wf[32];
#pragma unroll
  for (int ks = 0; ks < 32; ++ks) {
    uf[ks] = *(const long long*)(ubase + ks * 16);
    wf[ks] = *(const long long*)(wbase + ks * 16);
  }

  // ---- staging: unit u=tid; pair p=u>>4, pos=u&15: e=pos>>3, j=(pos&7)^(p&7),
  //      row=2p+e. LDS addr = p*256 + e*128 + (j^(p&7))*16 (+q2*8 at read). ----
  const int sp = tid >> 4;
  const int spos = tid & 15;
  const int se = spos >> 3;
  const int sj = (spos & 7) ^ (sp & 7);
  const int srow = 2 * sp + se;
  const unsigned char* fsrc = fb + (size_t)srow * K_ + sj * 16;  // + tt*64*512 + kc*128
  char* const fdst = (char*)Ft + tid * 16;                        // + bsel*8192

  // ---- frag read base: row r = wj*32 + c32 ----
  const int fp = wj * 16 + (c32 >> 1);
  const int fbase = fp * 256 + (c32 & 1) * 128 + q2 * 8;
  const int pmx = (fp & 7) << 4;

  f32x16 accS, accV;
  float num[16], den[16];
#pragma unroll
  for (int r = 0; r < 16; ++r) {
    accS[r] = 0.f; accV[r] = 0.f; num[r] = 0.f; den[r] = 0.f;
  }

  // stage it 0 into buffer 0
  gld_lds16(fsrc, fdst);

  for (int tt = 0; tt < 32; ++tt) {
#pragma unroll
    for (int kc = 0; kc < 4; ++kc) {
      const int it = tt * 4 + kc;
      const int bsel = it & 1;
      __syncthreads();   // buf[bsel] staged; prior reads of buf[bsel^1] done
      if (it != 127) {
        const int nit = it + 1;
        const int nofs = (nit >> 2) * (64 * K_) + (nit & 3) * 128;
        gld_lds16(fsrc + nofs, fdst + (bsel ^ 1) * 8192);
      }
      const char* fB = Ft[bsel];
#pragma unroll
      for (int ks = 0; ks < 8; ++ks) {
        long long bfr = *(const long long*)(fB + fbase + (pmx ^ (ks << 4)));
        accS = mfma32_fp8(uf[kc * 8 + ks], bfr, accS);
        accV = mfma32_fp8(wf[kc * 8 + ks], bfr, accV);
      }
    }
    // end of K for this 64-col t-tile: softmax-weighted accumulate, reset.
    // scores are O(0.01): exp without max-shift is safe.
#pragma unroll
    for (int r = 0; r < 16; ++r) {
      float p = __expf(accS[r] * INV_SS);
      den[r] += p;
      num[r] += p * (accV[r] * INV_SS);
      accS[r] = 0.f;
      accV[r] = 0.f;
    }
  }

  // reduce over 32 t-columns (c32 lanes; q2 halves hold different L-rows)
#pragma unroll
  for (int r = 0; r < 16; ++r) {
#pragma unroll
    for (int m = 1; m < 32; m <<= 1) {
      num[r] += __shfl_xor(num[r], m, 64);
      den[r] += __shfl_xor(den[r], m, 64);
    }
  }
  if (c32 == 0) {
#pragma unroll
    for (int r = 0; r < 16; ++r) {
      // C/D 32x32: row = (reg&3) + 8*(reg>>2) + 4*(lane>>5)
      int ll = wi * 32 + (r & 3) + 8 * (r >> 2) + 4 * q2;
      red[wj * 256 + ll] = num[r];
      red[wj * 256 + 128 + ll] = den[r];
    }
  }
  __syncthreads();
  if (tid < 128) {
    int l = l0 + tid;
    float n = red[tid] + red[256 + tid];
    float d = red[128 + tid] + red[384 + tid];
    out[(size_t)b * L_ + l] = n / d + final_b[l];
  }
}

// ---------------- BCE-with-logits mean ----------------
__global__ __launch_bounds__(256) void k_loss(const float* __restrict__ yhat,
                                              const float* __restrict__ target,
                                              float* __restrict__ loss) {
  int gid = blockIdx.x * 256 + threadIdx.x;
  float s = 0.f;
  for (int i = gid; i < B_ * L_; i += 64 * 256) {
    float y = yhat[i], t = target[i];
    s += fmaxf(y, 0.f) - y * t + log1pf(__expf(-fabsf(y)));
  }
#pragma unroll
  for (int m = 1; m < 64; m <<= 1) s += __shfl_xor(s, m, 64);
  if ((threadIdx.x & 63) == 0) atomicAdd(loss, s * (1.0f / (B_ * L_)));
}

extern "C" void kernel_launch(void* const* d_in, const int* in_sizes, int n_in,
                              void* d_out, int out_size, void* d_ws, size_t ws_size,
                              hipStream_t stream) {
  const int* ids = (const int*)d_in[0];
  const float* target = (const float*)d_in[3];
  const float* emb = (const float*)d_in[4];
  const float* conv_w = (const float*)d_in[5];
  const float* conv_b = (const float*)d_in[6];
  const float* U_w = (const float*)d_in[7];
  const float* F_w = (const float*)d_in[8];
  const float* final_b = (const float*)d_in[9];
  float* out = (float*)d_out;

  char* ws = (char*)d_ws;
  unsigned short* xpad = (unsigned short*)ws;                    // bf16 B*TP*E
  size_t off = (size_t)B_ * TP_ * E_ * 2;
  unsigned short* wt = (unsigned short*)(ws + off);              // bf16 K*KK
  off += (size_t)K_ * KK_ * 2;
  unsigned char* u8 = (unsigned char*)(ws + off);                // fp8 L*K
  off += (size_t)L_ * K_;
  unsigned char* f8 = (unsigned char*)(ws + off);                // fp8 L*K
  off += (size_t)L_ * K_;
  unsigned char* feats = (unsigned char*)(ws + off);             // fp8 B*T*K
  off += (size_t)B_ * T_ * K_;
  if (ws_size < off) return;

  k_embed<<<dim3((B_ * TP_ * 64) / 256), 256, 0, stream>>>(ids, emb, xpad);
  k_wt<<<dim3(KK_ / 256, K_), 256, 0, stream>>>(conv_w, wt);
  k_cast<<<dim3((L_ * K_ / 8) / 256, 2), 256, 0, stream>>>(U_w, F_w, u8, f8);
  k_conv<<<dim3(K_ / 128, T_ / 128, B_), 512, 0, stream>>>(xpad, wt, conv_b, feats);
  k_attn<<<dim3(L_ / 128, B_), 512, 0, stream>>>(feats, u8, f8, final_b, out);
  hipMemsetAsync(out + B_ * L_, 0, sizeof(float), stream);
  k_loss<<<dim3(64), 256, 0, stream>>>(out, target, out + B_ * L_);
}